// Round 15
// baseline (462.750 us; speedup 1.0000x reference)
//
#include <hip/hip_runtime.h>
#include <stdint.h>
#include <stddef.h>

typedef short v8s __attribute__((ext_vector_type(8)));
typedef float v4f __attribute__((ext_vector_type(4)));
typedef unsigned short v4u16 __attribute__((ext_vector_type(4)));

__device__ __forceinline__ unsigned short f2bf(float f) {
  union { float f; uint32_t u; } v; v.f = f;
  uint32_t r = (v.u + 0x7FFFu + ((v.u >> 16) & 1u)) >> 16;
  return (unsigned short)r;
}

__device__ __forceinline__ void gl_lds16(const void* g, void* l) {
  __builtin_amdgcn_global_load_lds(
      (__attribute__((address_space(1))) void*)(uintptr_t)(g),
      (__attribute__((address_space(3))) void*)(uintptr_t)(l), 16, 0, 0);
}

// ---------- prep: Us[o,k] = bf16(U[o,k] * relu(S[k]+delta[k])) ----------
__global__ __launch_bounds__(256) void k_prep_us(const float* __restrict__ U,
                                                 const float* __restrict__ S,
                                                 const float* __restrict__ delta,
                                                 unsigned short* __restrict__ Us) {
  int idx = blockIdx.x * 256 + threadIdx.x;
  int e0 = idx * 8;
  int col = e0 & 4095;
  float4 u0 = *(const float4*)(U + e0);
  float4 u1 = *(const float4*)(U + e0 + 4);
  float4 s0 = *(const float4*)(S + col);
  float4 s1 = *(const float4*)(S + col + 4);
  float4 d0 = *(const float4*)(delta + col);
  float4 d1 = *(const float4*)(delta + col + 4);
  float uu[8] = {u0.x, u0.y, u0.z, u0.w, u1.x, u1.y, u1.z, u1.w};
  float se[8] = {s0.x + d0.x, s0.y + d0.y, s0.z + d0.z, s0.w + d0.w,
                 s1.x + d1.x, s1.y + d1.y, s1.z + d1.z, s1.w + d1.w};
  v8s o;
#pragma unroll
  for (int j = 0; j < 8; ++j) {
    float sv = se[j] > 0.f ? se[j] : 0.f;
    o[j] = (short)f2bf(uu[j] * sv);
  }
  *(v8s*)(Us + e0) = o;
}

// ---------- prep: xb = bf16(x) ----------
__global__ __launch_bounds__(256) void k_prep_x(const float* __restrict__ in,
                                                unsigned short* __restrict__ out) {
  int idx = blockIdx.x * 256 + threadIdx.x;
  int e0 = idx * 8;
  float4 a = *(const float4*)(in + e0);
  float4 b = *(const float4*)(in + e0 + 4);
  float f[8] = {a.x, a.y, a.z, a.w, b.x, b.y, b.z, b.w};
  v8s o;
#pragma unroll
  for (int j = 0; j < 8; ++j) o[j] = (short)f2bf(f[j]);
  *(v8s*)(out + e0) = o;
}

// ---------- kron: Vo[k,i] = sum_j V[k,j] * (Q1xQ2xQ3)[i,j] ----------
__device__ __forceinline__ int PADI(int e) { return e + 4 * (e >> 6); }

__global__ __launch_bounds__(256) void k_kron(const float* __restrict__ V,
                                              const float* __restrict__ Q1,
                                              const float* __restrict__ Q2,
                                              const float* __restrict__ Q3,
                                              unsigned short* __restrict__ Vo) {
  __shared__ float bufA[4352];
  __shared__ float bufB[4352];
  __shared__ float q1s[256], q2s[256], q3s[256];
  int t = threadIdx.x;
  int row = blockIdx.x;
  q1s[t] = Q1[t]; q2s[t] = Q2[t]; q3s[t] = Q3[t];
  const float* vrow = V + (size_t)row * 4096;
#pragma unroll
  for (int i = 0; i < 4; ++i) {
    int idx = t + i * 256;
    float4 v = ((const float4*)vrow)[idx];
    int e = idx * 4;
    *(float4*)&bufA[PADI(e)] = v;
  }
  __syncthreads();
  {
    float r[16];
    int base = PADI(t * 16);
#pragma unroll
    for (int j3 = 0; j3 < 16; ++j3) r[j3] = bufA[base + j3];
#pragma unroll
    for (int i3 = 0; i3 < 16; ++i3) {
      float s = 0.f;
#pragma unroll
      for (int j3 = 0; j3 < 16; ++j3) s += r[j3] * q3s[i3 * 16 + j3];
      bufB[base + i3] = s;
    }
  }
  __syncthreads();
  {
    int j1 = t >> 4, i3 = t & 15;
    float r[16];
#pragma unroll
    for (int j2 = 0; j2 < 16; ++j2) r[j2] = bufB[PADI(j1 * 256 + j2 * 16 + i3)];
#pragma unroll
    for (int i2 = 0; i2 < 16; ++i2) {
      float s = 0.f;
#pragma unroll
      for (int j2 = 0; j2 < 16; ++j2) s += r[j2] * q2s[i2 * 16 + j2];
      bufA[PADI(j1 * 256 + i2 * 16 + i3)] = s;
    }
  }
  __syncthreads();
  {
    int i2 = t >> 4, i3 = t & 15;
    float r[16];
#pragma unroll
    for (int j1 = 0; j1 < 16; ++j1) r[j1] = bufA[PADI(j1 * 256 + i2 * 16 + i3)];
    unsigned short* orow = Vo + (size_t)row * 4096;
#pragma unroll
    for (int i1 = 0; i1 < 16; ++i1) {
      float s = 0.f;
#pragma unroll
      for (int j1 = 0; j1 < 16; ++j1) s += r[j1] * q1s[i1 * 16 + j1];
      orow[i1 * 256 + i2 * 16 + i3] = f2bf(s);
    }
  }
}

// ---------- transpose 4096x4096 bf16 ----------
__global__ __launch_bounds__(256) void k_transpose(const unsigned short* __restrict__ in,
                                                   unsigned short* __restrict__ out) {
  __shared__ unsigned short tile[64][68];
  int bx = blockIdx.x & 63;
  int by = blockIdx.x >> 6;
  int t = threadIdx.x;
#pragma unroll
  for (int q = 0; q < 4; ++q) {
    int i = t + q * 256;
    int r = i >> 4;
    int c = (i & 15) * 4;
    v4u16 v = *(const v4u16*)(in + (size_t)(by * 64 + r) * 4096 + bx * 64 + c);
    tile[r][c] = v[0]; tile[r][c + 1] = v[1]; tile[r][c + 2] = v[2]; tile[r][c + 3] = v[3];
  }
  __syncthreads();
#pragma unroll
  for (int q = 0; q < 4; ++q) {
    int i = t + q * 256;
    int r = i >> 4;
    int c = (i & 15) * 4;
    v4u16 v;
    v[0] = tile[c][r]; v[1] = tile[c + 1][r]; v[2] = tile[c + 2][r]; v[3] = tile[c + 3][r];
    *(v4u16*)(out + (size_t)(bx * 64 + r) * 4096 + by * 64 + c) = v;
  }
}

// ---------- 256x256 8-phase NT GEMM, reg-prefetch + T19 SGB interleave ----
// BM=BN=256, BK=64, 512 thr (2x4 waves), double-buffered swizzled LDS (128 KiB).
// Frags for phase p+1 prefetched into alternate registers during phase p; the
// sched_group_barrier template forces the emitted stream to INTERLEAVE
// {2 MFMA, 1 ds_read} so each read's issue/return hides in the matrix-pipe
// shadow instead of bursting (tests the VGPR-port-contention theory).
// Phase p: {STG; [SGB template: 2 VMEM + (2MFMA,1DS)x; setprio MFMA cluster];
//           [vmcnt(6) @Q3,Q7]; s_barrier}
// LDS regions (8192 shorts): idx = mat*4 + buf*2 + kh; [256 rows][32 shorts],
// byte swizzle f = c ^ (((row>>1)&3)<<4)  (measured 0 conflicts)

#define SGB __builtin_amdgcn_sched_group_barrier

#define STG(P0, P1, REGI, TT, KH) do {                                   \
    const unsigned short* _s0 = (P0) + (TT) * 64 + (KH) * 32;            \
    const unsigned short* _s1 = (P1) + (TT) * 64 + (KH) * 32;            \
    gl_lds16(_s0, &lds[(REGI) * 8192 + tid * 8]);                        \
    gl_lds16(_s1, &lds[(REGI) * 8192 + 4096 + tid * 8]);                 \
  } while (0)

#define RDA(BUF, KK, H, I) \
  (*(const v8s*)&lds[((BUF) * 2 + (KK)) * 8192 + (wr * 128 + (H) * 64 + (I) * 16) * 32 + acb])
#define RDB(BUF, KK, NN) \
  (*(const v8s*)&lds[(4 + (BUF) * 2 + (KK)) * 8192 + (wc * 64 + (NN) * 16) * 32 + acb])

#define LDA_SET(S, BUF, KK, H) do {                                       \
    aF[S][0] = RDA(BUF, KK, H, 0); aF[S][1] = RDA(BUF, KK, H, 1);         \
    aF[S][2] = RDA(BUF, KK, H, 2); aF[S][3] = RDA(BUF, KK, H, 3);         \
  } while (0)
#define LDB_SET(S, BUF, KK) do {                                          \
    bF[S][0] = RDB(BUF, KK, 0); bF[S][1] = RDB(BUF, KK, 1);               \
    bF[S][2] = RDB(BUF, KK, 2); bF[S][3] = RDB(BUF, KK, 3);               \
  } while (0)

#define MM(I, NN, AV, BV) \
  acc[(I)][(NN)] = __builtin_amdgcn_mfma_f32_16x16x32_bf16(AV, BV, acc[(I)][(NN)], 0, 0, 0)

// SGB templates: NRD = ds_reads this phase (8 or 4). VMEM first (stage issue),
// then interleave {2 MFMA, 1 DS_READ}, remainder MFMAs.
#define SGB8 do { SGB(0x10, 2, 0);                                        \
    SGB(0x8, 2, 0); SGB(0x100, 1, 0); SGB(0x8, 2, 0); SGB(0x100, 1, 0);   \
    SGB(0x8, 2, 0); SGB(0x100, 1, 0); SGB(0x8, 2, 0); SGB(0x100, 1, 0);   \
    SGB(0x8, 2, 0); SGB(0x100, 1, 0); SGB(0x8, 2, 0); SGB(0x100, 1, 0);   \
    SGB(0x8, 2, 0); SGB(0x100, 1, 0); SGB(0x8, 2, 0); SGB(0x100, 1, 0);   \
  } while (0)
#define SGB4 do { SGB(0x10, 2, 0);                                        \
    SGB(0x8, 2, 0); SGB(0x100, 1, 0); SGB(0x8, 2, 0); SGB(0x100, 1, 0);   \
    SGB(0x8, 2, 0); SGB(0x100, 1, 0); SGB(0x8, 2, 0); SGB(0x100, 1, 0);   \
    SGB(0x8, 8, 0);                                                       \
  } while (0)

#define PHASE(H, AS, BS, PRE, STAGES, DOVM, NRD) do {                     \
    STAGES;                                                               \
    PRE;                                                                  \
    __builtin_amdgcn_s_setprio(1);                                        \
    MM((H)*4+0, 0, aF[AS][0], bF[BS][0]); MM((H)*4+1, 0, aF[AS][1], bF[BS][0]); \
    MM((H)*4+2, 0, aF[AS][2], bF[BS][0]); MM((H)*4+3, 0, aF[AS][3], bF[BS][0]); \
    MM((H)*4+0, 1, aF[AS][0], bF[BS][1]); MM((H)*4+1, 1, aF[AS][1], bF[BS][1]); \
    MM((H)*4+2, 1, aF[AS][2], bF[BS][1]); MM((H)*4+3, 1, aF[AS][3], bF[BS][1]); \
    MM((H)*4+0, 2, aF[AS][0], bF[BS][2]); MM((H)*4+1, 2, aF[AS][1], bF[BS][2]); \
    MM((H)*4+2, 2, aF[AS][2], bF[BS][2]); MM((H)*4+3, 2, aF[AS][3], bF[BS][2]); \
    MM((H)*4+0, 3, aF[AS][0], bF[BS][3]); MM((H)*4+1, 3, aF[AS][1], bF[BS][3]); \
    MM((H)*4+2, 3, aF[AS][2], bF[BS][3]); MM((H)*4+3, 3, aF[AS][3], bF[BS][3]); \
    __builtin_amdgcn_s_setprio(0);                                        \
    if (NRD == 8) SGB8; else SGB4;                                        \
    if (DOVM) asm volatile("s_waitcnt vmcnt(6)" ::: "memory");            \
    __builtin_amdgcn_s_barrier();                                         \
    __builtin_amdgcn_sched_barrier(0);                                    \
  } while (0)

template <int OUT_BF16>
__global__ __launch_bounds__(512, 2) void k_gemm256(const unsigned short* __restrict__ A,
                                                    const unsigned short* __restrict__ B,
                                                    void* __restrict__ Cv,
                                                    int K, int N, int nbn) {
  __shared__ unsigned short lds[65536];  // 128 KiB
  const int NT = K >> 6;
  int nwg = gridDim.x;
  int bid = blockIdx.x;
  int wg = (bid & 7) * (nwg >> 3) + (bid >> 3);  // bijective XCD swizzle (nwg%8==0)
  int bm = wg / nbn, bn = wg % nbn;
  int tid = threadIdx.x;
  int lane = tid & 63;
  int wid = tid >> 6;
  int wr = wid >> 2, wc = wid & 3;

  const unsigned short* Ab = A + (size_t)bm * 256 * K;
  const unsigned short* Bb = B + (size_t)bn * 256 * K;

  // staging source (pre-swizzled): thread covers rows srow / srow+128, 16 B each
  int srow = tid >> 2;
  int scol = 8 * ((tid & 3) ^ ((tid >> 3) & 3));
  const unsigned short* As0 = Ab + (size_t)srow * K + scol;
  const unsigned short* As1 = As0 + (size_t)128 * K;
  const unsigned short* Bs0 = Bb + (size_t)srow * K + scol;
  const unsigned short* Bs1 = Bs0 + (size_t)128 * K;

  // frag-read lane constant (shorts): row (lane&15), 16B slot (lane>>4) ^ swz
  int acb = (lane & 15) * 32 + (((((lane >> 4) << 4) ^ ((((lane & 15) >> 1) & 3) << 4)) >> 1));

  v4f acc[8][4];
#pragma unroll
  for (int i = 0; i < 8; ++i)
#pragma unroll
    for (int j = 0; j < 4; ++j) acc[i][j] = (v4f){0.f, 0.f, 0.f, 0.f};
  v8s aF[2][4];
  v8s bF[2][4];

  // prologue: stage tile0 {B-kh0, A-kh0, B-kh1, A-kh1}, tile1 {B-kh0, A-kh0, B-kh1}
  STG(Bs0, Bs1, 4, 0, 0); STG(As0, As1, 0, 0, 0);
  STG(Bs0, Bs1, 5, 0, 1); STG(As0, As1, 1, 0, 1);
  STG(Bs0, Bs1, 6, 1, 0); STG(As0, As1, 2, 1, 0);
  STG(Bs0, Bs1, 7, 1, 1);
  asm volatile("s_waitcnt vmcnt(6)" ::: "memory");
  __builtin_amdgcn_s_barrier();
  __builtin_amdgcn_sched_barrier(0);
  // preload phase-0 fragments (regions 0 and 4 landed in the vmcnt(6) drain)
  LDA_SET(0, 0, 0, 0);
  LDB_SET(0, 0, 0);

  for (int it = 0; it < NT / 2; ++it) {
    int t1 = 2 * it + 1;
    int s0 = (2 * it + 2) & (NT - 1);
    int s1 = (2 * it + 3) & (NT - 1);
    // p: MFMA(buf,kk,H) uses (AS,BS); PRE loads frags for p+1; STG region sched
    PHASE(0, 0, 0, LDA_SET(1, 0, 0, 1),                    STG(As0, As1, 3, t1, 1), 0, 4);
    PHASE(1, 1, 0, LDA_SET(0, 0, 1, 0); LDB_SET(1, 0, 1),  STG(Bs0, Bs1, 4, s0, 0), 0, 8);
    PHASE(0, 0, 1, LDA_SET(1, 0, 1, 1),                    STG(As0, As1, 0, s0, 0), 0, 4);
    PHASE(1, 1, 1, LDA_SET(0, 1, 0, 0); LDB_SET(0, 1, 0),  STG(Bs0, Bs1, 5, s0, 1), 1, 8);
    PHASE(0, 0, 0, LDA_SET(1, 1, 0, 1),                    STG(As0, As1, 1, s0, 1), 0, 4);
    PHASE(1, 1, 0, LDA_SET(0, 1, 1, 0); LDB_SET(1, 1, 1),  STG(Bs0, Bs1, 6, s1, 0), 0, 8);
    PHASE(0, 0, 1, LDA_SET(1, 1, 1, 1),                    STG(As0, As1, 2, s1, 0), 0, 4);
    PHASE(1, 1, 1, LDA_SET(0, 0, 0, 0); LDB_SET(0, 0, 0),  STG(Bs0, Bs1, 7, s1, 1), 1, 8);
  }
  asm volatile("s_waitcnt vmcnt(0)" ::: "memory");

  int row0 = bm * 256 + wr * 128 + ((lane >> 4) << 2);
  int col0 = bn * 256 + wc * 64 + (lane & 15);
  if (OUT_BF16) {
    unsigned short* Cp = (unsigned short*)Cv;
#pragma unroll
    for (int m = 0; m < 8; ++m)
#pragma unroll
      for (int n = 0; n < 4; ++n)
#pragma unroll
        for (int r = 0; r < 4; ++r)
          Cp[(size_t)(row0 + m * 16 + r) * N + col0 + n * 16] = f2bf(acc[m][n][r]);
  } else {
    float* Cp = (float*)Cv;
#pragma unroll
    for (int m = 0; m < 8; ++m)
#pragma unroll
      for (int n = 0; n < 4; ++n)
#pragma unroll
        for (int r = 0; r < 4; ++r)
          Cp[(size_t)(row0 + m * 16 + r) * N + col0 + n * 16] = acc[m][n][r];
  }
}

extern "C" void kernel_launch(void* const* d_in, const int* in_sizes, int n_in,
                              void* d_out, int out_size, void* d_ws, size_t ws_size,
                              hipStream_t stream) {
  const float* x = (const float*)d_in[0];
  const float* U = (const float*)d_in[1];
  const float* S = (const float*)d_in[2];
  const float* V = (const float*)d_in[3];
  const float* delta = (const float*)d_in[4];
  const float* Q1 = (const float*)d_in[5];
  const float* Q2 = (const float*)d_in[6];
  const float* Q3 = (const float*)d_in[7];

  char* ws = (char*)d_ws;
  unsigned short* Us = (unsigned short*)(ws);
  unsigned short* Mt = (unsigned short*)(ws + 33554432);
  unsigned short* xb = (unsigned short*)(ws + 67108864);
  char* oc = (char*)d_out;
  unsigned short* Vo = (unsigned short*)(oc);
  unsigned short* VoT = (unsigned short*)(oc + 33554432);
  float* out = (float*)d_out;

  k_prep_us<<<8192, 256, 0, stream>>>(U, S, delta, Us);
  k_kron<<<4096, 256, 0, stream>>>(V, Q1, Q2, Q3, Vo);
  k_transpose<<<4096, 256, 0, stream>>>(Vo, VoT);
  k_prep_x<<<16384, 256, 0, stream>>>(x, xb);
  // Mt[o,i] = sum_k Us[o,k] * VoT[i,k]   (4096x4096x4096)
  k_gemm256<1><<<256, 512, 0, stream>>>(Us, VoT, (void*)Mt, 4096, 4096, 16);
  // out[n,o] = sum_i xb[n,i] * Mt[o,i]   (8192x4096x4096)
  k_gemm256<0><<<512, 512, 0, stream>>>(xb, Mt, (void*)out, 4096, 4096, 16);
}